// Round 5
// baseline (1447.798 us; speedup 1.0000x reference)
//
#include <hip/hip_runtime.h>
#include <math.h>

#define NPTS 4096
#define MC   1024
#define KNB  32

typedef __attribute__((ext_vector_type(8))) short bf16x8;
typedef __attribute__((ext_vector_type(4))) float f32x4;
typedef __attribute__((ext_vector_type(2))) float f32x2;

__device__ __forceinline__ unsigned short f2bf(float f) {
  unsigned int u = __float_as_uint(f);
  u = u + 0x7fffu + ((u >> 16) & 1u);   // round-to-nearest-even
  return (unsigned short)(u >> 16);
}

template <int CTRL>
__device__ __forceinline__ float dpp_max(float v) {
  int o = __builtin_amdgcn_update_dpp(__float_as_int(v), __float_as_int(v), CTRL, 0xF, 0xF, false);
  return fmaxf(v, __int_as_float(o));
}

// ---------------------------------------------------------------------------
// Kernel 1: farthest point sampling. One block per batch, 256 threads
// (4 waves) — the ONLY geometry where the compiler keeps 64+ per-lane array
// VGPRs resident (R3: VGPR=88 ok; 512-thr variants spilled to 32-36 VGPRs).
// 16 points per lane as f32x2 pairs (v_pk_* math, contract OFF = bit-exact
// mul-then-add). Per iteration:
//   pk dist update -> per-lane scalar max tree -> value-only DPP wave max ->
//   16 ballots + SALU ctz scan recover lowest-index argmax -> winning lane
//   publishes key+coords to double-buffered LDS slots -> ONE barrier ->
//   all lanes read 4 keys+coords in parallel, select max key.
// Key = (f32bits(dist)<<32) | ~idx: u64 max == argmax w/ lowest-index
// tie-break (exact jnp.argmax semantics).
// ---------------------------------------------------------------------------
__global__ __launch_bounds__(256, 1) void fps_kernel(const float* __restrict__ points,
                                                     float* __restrict__ out_cent) {
  __shared__ __align__(16) unsigned long long skey[2][4];
  __shared__ __align__(16) float4 scoord[2][4];
  __shared__ float slog[3][MC];
  const int b = blockIdx.x, t = threadIdx.x;
  const int w = t >> 6, lane = t & 63;
  const float* pb = points + (size_t)b * 3 * NPTS;

  // lane owns global idx = k*1024 + t*4 + (2*p+e); k in 0..3, p,e in {0,1}
  f32x2 fx[4][2], fy[4][2], fz[4][2], dst[4][2];
#pragma unroll
  for (int k = 0; k < 4; ++k) {
    float4 X = ((const float4*)pb)[k * 256 + t];
    float4 Y = ((const float4*)(pb + NPTS))[k * 256 + t];
    float4 Z = ((const float4*)(pb + 2 * NPTS))[k * 256 + t];
    fx[k][0] = (f32x2){X.x, X.y}; fx[k][1] = (f32x2){X.z, X.w};
    fy[k][0] = (f32x2){Y.x, Y.y}; fy[k][1] = (f32x2){Y.z, Y.w};
    fz[k][0] = (f32x2){Z.x, Z.y}; fz[k][1] = (f32x2){Z.z, Z.w};
    dst[k][0] = (f32x2){1e10f, 1e10f};
    dst[k][1] = (f32x2){1e10f, 1e10f};
  }
  float lx = pb[0], ly = pb[NPTS], lz = pb[2 * NPTS];

  for (int i = 0; i < MC; ++i) {
    if (t == 0) { slog[0][i] = lx; slog[1][i] = ly; slog[2][i] = lz; }
    if (i == MC - 1) break;

    // ---- distance update (bit-exact: no contraction), packed f32 ----
    {
#pragma clang fp contract(off)
      const f32x2 lx2 = (f32x2){lx, lx};
      const f32x2 ly2 = (f32x2){ly, ly};
      const f32x2 lz2 = (f32x2){lz, lz};
#pragma unroll
      for (int k = 0; k < 4; ++k)
#pragma unroll
        for (int p = 0; p < 2; ++p) {
          f32x2 dx = fx[k][p] - lx2;
          f32x2 dy = fy[k][p] - ly2;
          f32x2 dz = fz[k][p] - lz2;
          f32x2 d  = (dx * dx + dy * dy) + dz * dz;
          f32x2 nd;
          nd.x = fminf(dst[k][p].x, d.x);
          nd.y = fminf(dst[k][p].y, d.y);
          dst[k][p] = nd;
        }
    }

    // ---- per-lane max of 16, then value-only wave64 max via DPP ----
    float m = -1.0f;
#pragma unroll
    for (int k = 0; k < 4; ++k)
#pragma unroll
      for (int p = 0; p < 2; ++p)
        m = fmaxf(m, fmaxf(dst[k][p].x, dst[k][p].y));
    m = dpp_max<0x111>(m);   // row_shr:1
    m = dpp_max<0x112>(m);   // row_shr:2
    m = dpp_max<0x114>(m);   // row_shr:4
    m = dpp_max<0x118>(m);   // row_shr:8
    m = dpp_max<0x142>(m);   // row_bcast:15
    m = dpp_max<0x143>(m);   // row_bcast:31
    const float wv = __int_as_float(__builtin_amdgcn_readlane(__float_as_int(m), 63));

    // ---- recover lowest matching index: 16 ballots + scalar scan ----
    unsigned long long mk[4][4];
#pragma unroll
    for (int k = 0; k < 4; ++k) {
      mk[k][0] = __ballot(dst[k][0].x == wv);
      mk[k][1] = __ballot(dst[k][0].y == wv);
      mk[k][2] = __ballot(dst[k][1].x == wv);
      mk[k][3] = __ballot(dst[k][1].y == wv);
    }
    int sel_l = -1, sel_k = 0, sel_c = 0;
#pragma unroll
    for (int k = 0; k < 4; ++k) {
      if (sel_l < 0) {
        unsigned long long any = mk[k][0] | mk[k][1] | mk[k][2] | mk[k][3];
        if (any) {
          sel_l = __builtin_ctzll(any);
          const unsigned long long bit = 1ull << sel_l;
          sel_k = k;
          sel_c = (mk[k][0] & bit) ? 0 : (mk[k][1] & bit) ? 1 : (mk[k][2] & bit) ? 2 : 3;
        }
      }
    }
    const int nb = i & 1;
    if (sel_l < 0) {
      // this wave doesn't hold the global max; publish sentinel (< any real key)
      if (lane == 0) skey[nb][w] = 0ull;
    } else {
      const int selIdx = sel_k * 1024 + (w * 64 + sel_l) * 4 + sel_c;
      if (lane == sel_l) {
        skey[nb][w] = ((unsigned long long)__float_as_uint(wv) << 32) | (unsigned int)~selIdx;
        // extract the winning element's coords (sel_k/sel_c wave-uniform)
        float ox = 0.f, oy = 0.f, oz = 0.f;
#pragma unroll
        for (int k = 0; k < 4; ++k)
#pragma unroll
          for (int c = 0; c < 4; ++c) {
            const bool h = (sel_k == k) && (sel_c == c);
            const int p = c >> 1;
            ox = h ? ((c & 1) ? fx[k][p].y : fx[k][p].x) : ox;
            oy = h ? ((c & 1) ? fy[k][p].y : fy[k][p].x) : oy;
            oz = h ? ((c & 1) ? fz[k][p].y : fz[k][p].x) : oz;
          }
        scoord[nb][w] = make_float4(ox, oy, oz, 0.0f);
      }
    }
    __syncthreads();

    // ---- all lanes: parallel read of 4 keys + coords, select winner ----
    unsigned long long k0 = skey[nb][0], k1 = skey[nb][1];
    unsigned long long k2 = skey[nb][2], k3 = skey[nb][3];
    float4 c0 = scoord[nb][0], c1 = scoord[nb][1];
    float4 c2 = scoord[nb][2], c3 = scoord[nb][3];
    unsigned long long ka = k0; float4 ca = c0;
    if (k1 > ka) { ka = k1; ca = c1; }
    unsigned long long kb = k2; float4 cb = c2;
    if (k3 > kb) { kb = k3; cb = c3; }
    if (kb > ka) { ca = cb; }
    lx = ca.x; ly = ca.y; lz = ca.z;
  }
  __syncthreads();
  // coalesced centroid output [3][1024] per batch
  float* oc = out_cent + (size_t)b * 3 * MC;
#pragma unroll
  for (int k = 0; k < 12; ++k) {
    int idx = t + k * 256;
    oc[idx] = ((const float*)slog)[idx];
  }
}

// ---------------------------------------------------------------------------
// Kernel 2: features [B,64,N] fp32 -> featsT [B,N,64] bf16 (tiled transpose)
// ---------------------------------------------------------------------------
__global__ __launch_bounds__(256) void transpose_feats(const float* __restrict__ feats,
                                                       unsigned short* __restrict__ featsT) {
  __shared__ float tile[64][65];
  const int blk = blockIdx.x;
  const int b = blk >> 6;
  const int n0 = (blk & 63) * 64;
  const int t = threadIdx.x;
  const float* src = feats + (size_t)b * 64 * NPTS;
  {
    const int n = t & 63, cbase = t >> 6;
#pragma unroll
    for (int j = 0; j < 16; ++j) {
      int c = cbase + j * 4;
      tile[c][n] = src[(size_t)c * NPTS + n0 + n];
    }
  }
  __syncthreads();
  {
    const int c = t & 63, nbase = t >> 6;
    unsigned short* dst = featsT + ((size_t)b * NPTS + n0) * 64;
#pragma unroll
    for (int j = 0; j < 16; ++j) {
      int n = nbase + j * 4;
      dst[(size_t)n * 64 + c] = f2bf(tile[c][n]);
    }
  }
}

// ---------------------------------------------------------------------------
// Kernel 3: pack W1/W2/W3 into MFMA B-fragment order (bf16), with the layer-1
// column remap: X cols 0..63 = gfeat (ref cols 3..66), 64..66 = local xyz,
// 67..95 = zero pad.
// ---------------------------------------------------------------------------
__global__ __launch_bounds__(64) void pack_w(const float* __restrict__ w1,
                                             const float* __restrict__ w2,
                                             const float* __restrict__ w3,
                                             unsigned short* __restrict__ wpack) {
  const int f = blockIdx.x, lane = threadIdx.x;
  int layer, kt, nt;
  if (f < 12)      { layer = 0; kt = f >> 2;        nt = f & 3; }
  else if (f < 20) { layer = 1; kt = (f - 12) >> 2; nt = (f - 12) & 3; }
  else             { layer = 2; kt = (f - 20) >> 3; nt = (f - 20) & 7; }
  const int o = nt * 16 + (lane & 15);
  unsigned short* dst = wpack + ((size_t)f * 64 + lane) * 8;
#pragma unroll
  for (int j = 0; j < 8; ++j) {
    int k = kt * 32 + (lane >> 4) * 8 + j;
    float x = 0.0f;
    if (layer == 0)      { if (k < 67) { int cin = (k < 64) ? (k + 3) : (k - 64); x = w1[o * 67 + cin]; } }
    else if (layer == 1) { x = w2[o * 64 + k]; }
    else                 { x = w3[o * 64 + k]; }
    dst[j] = f2bf(x);
  }
}

// ---------------------------------------------------------------------------
// Kernel 4: ball query. Centroids read from out_cent layout [B,3,MC].
// ---------------------------------------------------------------------------
__global__ __launch_bounds__(256) void ball_query_kernel(const float* __restrict__ points,
                                                         const float* __restrict__ cent,
                                                         int* __restrict__ nidx) {
  __shared__ float sx[NPTS], sy[NPTS], sz[NPTS];
  __shared__ int lists[4][KNB];
  const int b  = blockIdx.x >> 4;
  const int cb = blockIdx.x & 15;
  const int t = threadIdx.x;
  const float* pb = points + (size_t)b * 3 * NPTS;
#pragma unroll
  for (int j = 0; j < 4; ++j) {
    int i4 = t + j * 256;
    ((float4*)sx)[i4] = ((const float4*)pb)[i4];
    ((float4*)sy)[i4] = ((const float4*)(pb + NPTS))[i4];
    ((float4*)sz)[i4] = ((const float4*)(pb + 2 * NPTS))[i4];
  }
  __syncthreads();
  const int w = t >> 6, lane = t & 63;
  const float R2 = (float)(0.2 * 0.2);
  const float* cbp = cent + (size_t)b * 3 * MC;
  for (int cm = 0; cm < 16; ++cm) {
    const int m  = cb * 64 + w * 16 + cm;
    const int bm = b * MC + m;
    const float cx = cbp[m], cy = cbp[MC + m], cz = cbp[2 * MC + m];
    const float c2 = __fadd_rn(__fadd_rn(__fmul_rn(cx, cx), __fmul_rn(cy, cy)), __fmul_rn(cz, cz));
    int cnt = 0;
    for (int ch = 0; ch < 64; ++ch) {
      const int n = ch * 64 + lane;
      float x = sx[n], y = sy[n], z = sz[n];
      float p2  = __fadd_rn(__fadd_rn(__fmul_rn(x, x),  __fmul_rn(y, y)),  __fmul_rn(z, z));
      float dot = __fadd_rn(__fadd_rn(__fmul_rn(cx, x), __fmul_rn(cy, y)), __fmul_rn(cz, z));
      float d2  = __fsub_rn(__fadd_rn(c2, p2), __fmul_rn(2.0f, dot));
      bool hit = (d2 <= R2);
      unsigned long long msk = __ballot(hit);
      if (hit) {
        int pos = cnt + __popcll(msk & ((1ull << lane) - 1ull));
        if (pos < KNB) lists[w][pos] = n;
      }
      cnt += __popcll(msk);
      if (cnt >= KNB) break;
    }
    if (lane < KNB) {
      int first = lists[w][0];
      int v = (lane < cnt) ? lists[w][lane] : first;
      nidx[(size_t)bm * KNB + lane] = v;
    }
  }
}

// ---------------------------------------------------------------------------
// Kernel 5: fused gather + 3-layer MLP (bf16 MFMA 16x16x32) + maxpool.
// Hs is wave-private: no block barriers between layers, only
// __threadfence_block(). obuf stride 20 kills the 16-way bank conflict.
// ---------------------------------------------------------------------------
__global__ __launch_bounds__(256) void mlp_kernel(
    const float* __restrict__ points,
    const float* __restrict__ cent,
    const int* __restrict__ nidx,
    const unsigned short* __restrict__ featsT,
    const unsigned short* __restrict__ wpack,
    const float* __restrict__ b1, const float* __restrict__ g1, const float* __restrict__ be1,
    const float* __restrict__ b2, const float* __restrict__ g2, const float* __restrict__ be2,
    const float* __restrict__ b3, const float* __restrict__ g3, const float* __restrict__ be3,
    float* __restrict__ out) {
  __shared__ __align__(16) unsigned short Hs[4][2][32 * 72];
  __shared__ __align__(16) float obuf[128 * 20];
  const int t = threadIdx.x;
  const int w = t >> 6, lane = t & 63;
  const int r = lane & 15, q = lane >> 4;
  const float inv_s = 1.0f / sqrtf(1.0f + 1e-5f);

  float pb1[4], ps1[4], pe1[4], pb2[4], ps2[4], pe2[4], pb3[8], ps3[8], pe3[8];
#pragma unroll
  for (int nt = 0; nt < 4; ++nt) {
    int o = nt * 16 + r;
    pb1[nt] = b1[o]; ps1[nt] = g1[o] * inv_s; pe1[nt] = be1[o];
    pb2[nt] = b2[o]; ps2[nt] = g2[o] * inv_s; pe2[nt] = be2[o];
  }
#pragma unroll
  for (int nt = 0; nt < 8; ++nt) {
    int o = nt * 16 + r;
    pb3[nt] = b3[o]; ps3[nt] = g3[o] * inv_s; pe3[nt] = be3[o];
  }
  const int bm0 = blockIdx.x * 16;
  const int b   = bm0 >> 10;
  const int m0  = bm0 & 1023;
  const float* ptsb = points + (size_t)b * 3 * NPTS;
  const float* cbp  = cent + (size_t)b * 3 * MC;

  for (int it = 0; it < 4; ++it) {
    const int ml = it * 4 + w;
    const int bm = bm0 + ml;
    const int m  = bm & 1023;
    const int n0 = nidx[(size_t)bm * KNB + r];
    const int n1 = nidx[(size_t)bm * KNB + 16 + r];
    const float cx = cbp[m], cy = cbp[MC + m], cz = cbp[2 * MC + m];

    // ---- layer 1 ----
    bf16x8 aF[2][2];
#pragma unroll
    for (int mt = 0; mt < 2; ++mt) {
      int n = mt ? n1 : n0;
      const unsigned short* rowp = featsT + ((size_t)b * NPTS + n) * 64 + q * 8;
      aF[mt][0] = *(const bf16x8*)(rowp);
      aF[mt][1] = *(const bf16x8*)(rowp + 32);
    }
    bf16x8 aL[2];
#pragma unroll
    for (int mt = 0; mt < 2; ++mt) {
      bf16x8 a = {0, 0, 0, 0, 0, 0, 0, 0};
      if (q == 0) {
        int n = mt ? n1 : n0;
        a[0] = (short)f2bf(ptsb[n] - cx);
        a[1] = (short)f2bf(ptsb[NPTS + n] - cy);
        a[2] = (short)f2bf(ptsb[2 * NPTS + n] - cz);
      }
      aL[mt] = a;
    }
    f32x4 acc1[2][4];
#pragma unroll
    for (int mt = 0; mt < 2; ++mt)
#pragma unroll
      for (int nt = 0; nt < 4; ++nt) acc1[mt][nt] = (f32x4){0.f, 0.f, 0.f, 0.f};
#pragma unroll
    for (int kt = 0; kt < 3; ++kt) {
#pragma unroll
      for (int nt = 0; nt < 4; ++nt) {
        bf16x8 wf = *(const bf16x8*)(wpack + ((size_t)(kt * 4 + nt) * 64 + lane) * 8);
#pragma unroll
        for (int mt = 0; mt < 2; ++mt) {
          bf16x8 a = (kt < 2) ? aF[mt][kt] : aL[mt];
          acc1[mt][nt] = __builtin_amdgcn_mfma_f32_16x16x32_bf16(a, wf, acc1[mt][nt], 0, 0, 0);
        }
      }
    }
#pragma unroll
    for (int mt = 0; mt < 2; ++mt)
#pragma unroll
      for (int nt = 0; nt < 4; ++nt)
#pragma unroll
        for (int rr = 0; rr < 4; ++rr) {
          float y = (acc1[mt][nt][rr] + pb1[nt]) * ps1[nt] + pe1[nt];
          y = fmaxf(y, 0.0f);
          Hs[w][0][(mt * 16 + q * 4 + rr) * 72 + nt * 16 + r] = f2bf(y);
        }
    __threadfence_block();

    // ---- layer 2 ----
    f32x4 acc2[2][4];
#pragma unroll
    for (int mt = 0; mt < 2; ++mt)
#pragma unroll
      for (int nt = 0; nt < 4; ++nt) acc2[mt][nt] = (f32x4){0.f, 0.f, 0.f, 0.f};
#pragma unroll
    for (int kt = 0; kt < 2; ++kt) {
      bf16x8 a0 = *(const bf16x8*)&Hs[w][0][(0 * 16 + r) * 72 + kt * 32 + q * 8];
      bf16x8 a1 = *(const bf16x8*)&Hs[w][0][(1 * 16 + r) * 72 + kt * 32 + q * 8];
#pragma unroll
      for (int nt = 0; nt < 4; ++nt) {
        bf16x8 wf = *(const bf16x8*)(wpack + ((size_t)(12 + kt * 4 + nt) * 64 + lane) * 8);
        acc2[0][nt] = __builtin_amdgcn_mfma_f32_16x16x32_bf16(a0, wf, acc2[0][nt], 0, 0, 0);
        acc2[1][nt] = __builtin_amdgcn_mfma_f32_16x16x32_bf16(a1, wf, acc2[1][nt], 0, 0, 0);
      }
    }
#pragma unroll
    for (int mt = 0; mt < 2; ++mt)
#pragma unroll
      for (int nt = 0; nt < 4; ++nt)
#pragma unroll
        for (int rr = 0; rr < 4; ++rr) {
          float y = (acc2[mt][nt][rr] + pb2[nt]) * ps2[nt] + pe2[nt];
          y = fmaxf(y, 0.0f);
          Hs[w][1][(mt * 16 + q * 4 + rr) * 72 + nt * 16 + r] = f2bf(y);
        }
    __threadfence_block();

    // ---- layer 3 + maxpool ----
    f32x4 acc3[2][8];
#pragma unroll
    for (int mt = 0; mt < 2; ++mt)
#pragma unroll
      for (int nt = 0; nt < 8; ++nt) acc3[mt][nt] = (f32x4){0.f, 0.f, 0.f, 0.f};
#pragma unroll
    for (int kt = 0; kt < 2; ++kt) {
      bf16x8 a0 = *(const bf16x8*)&Hs[w][1][(0 * 16 + r) * 72 + kt * 32 + q * 8];
      bf16x8 a1 = *(const bf16x8*)&Hs[w][1][(1 * 16 + r) * 72 + kt * 32 + q * 8];
#pragma unroll
      for (int nt = 0; nt < 8; ++nt) {
        bf16x8 wf = *(const bf16x8*)(wpack + ((size_t)(20 + kt * 8 + nt) * 64 + lane) * 8);
        acc3[0][nt] = __builtin_amdgcn_mfma_f32_16x16x32_bf16(a0, wf, acc3[0][nt], 0, 0, 0);
        acc3[1][nt] = __builtin_amdgcn_mfma_f32_16x16x32_bf16(a1, wf, acc3[1][nt], 0, 0, 0);
      }
    }
#pragma unroll
    for (int nt = 0; nt < 8; ++nt) {
      float pm = 0.0f;   // relu outputs are >= 0
#pragma unroll
      for (int mt = 0; mt < 2; ++mt)
#pragma unroll
        for (int rr = 0; rr < 4; ++rr) {
          float y = (acc3[mt][nt][rr] + pb3[nt]) * ps3[nt] + pe3[nt];
          y = fmaxf(y, 0.0f);
          pm = fmaxf(pm, y);
        }
      pm = fmaxf(pm, __shfl_xor(pm, 16));
      pm = fmaxf(pm, __shfl_xor(pm, 32));
      if (q == 0) obuf[(nt * 16 + r) * 20 + ml] = pm;
    }
    __threadfence_block();
  }
  __syncthreads();
  // coalesced-ish store: thread t -> channel t>>1, half (t&1)*8
  {
    const int ch = t >> 1, mh = (t & 1) * 8;
    float4 u0 = *(const float4*)&obuf[ch * 20 + mh];
    float4 u1 = *(const float4*)&obuf[ch * 20 + mh + 4];
    float* outp = out + ((size_t)b * 128 + ch) * 1024 + m0 + mh;
    *(float4*)(outp)     = u0;
    *(float4*)(outp + 4) = u1;
  }
}

// ---------------------------------------------------------------------------
extern "C" void kernel_launch(void* const* d_in, const int* in_sizes, int n_in,
                              void* d_out, int out_size, void* d_ws, size_t ws_size,
                              hipStream_t stream) {
  (void)in_sizes; (void)n_in; (void)out_size; (void)ws_size;
  const float* points   = (const float*)d_in[0];
  const float* features = (const float*)d_in[1];
  const float* w1  = (const float*)d_in[2];
  const float* b1  = (const float*)d_in[3];
  const float* g1  = (const float*)d_in[4];
  const float* be1 = (const float*)d_in[5];
  const float* w2  = (const float*)d_in[6];
  const float* b2  = (const float*)d_in[7];
  const float* g2  = (const float*)d_in[8];
  const float* be2 = (const float*)d_in[9];
  const float* w3  = (const float*)d_in[10];
  const float* b3  = (const float*)d_in[11];
  const float* g3  = (const float*)d_in[12];
  const float* be3 = (const float*)d_in[13];

  float* outc = (float*)d_out;                  // centroids [16,3,1024]
  float* outf = outc + 16 * 3 * 1024;           // features  [16,128,1024]

  char* ws = (char*)d_ws;
  int*            nidx    = (int*)(ws);                      // 16384*32*4  = 2 MiB
  unsigned short* featsT  = (unsigned short*)(ws + 0x200000);// 16*4096*64*2= 8 MiB
  unsigned short* wpack   = (unsigned short*)(ws + 0xA00000);// 36*1024 B

  fps_kernel<<<16, 256, 0, stream>>>(points, outc);
  transpose_feats<<<1024, 256, 0, stream>>>(features, featsT);
  pack_w<<<36, 64, 0, stream>>>(w1, w2, w3, wpack);
  ball_query_kernel<<<256, 256, 0, stream>>>(points, outc, nidx);
  mlp_kernel<<<1024, 256, 0, stream>>>(points, outc, nidx, featsT, wpack,
                                       b1, g1, be1, b2, g2, be2, b3, g3, be3, outf);
}

// Round 6
// 979.661 us; speedup vs baseline: 1.4779x; 1.4779x over previous
//
#include <hip/hip_runtime.h>
#include <math.h>

#define NPTS 4096
#define MC   1024
#define KNB  32

typedef __attribute__((ext_vector_type(8))) short bf16x8;
typedef __attribute__((ext_vector_type(4))) float f32x4;

__device__ __forceinline__ unsigned short f2bf(float f) {
  unsigned int u = __float_as_uint(f);
  u = u + 0x7fffu + ((u >> 16) & 1u);   // round-to-nearest-even
  return (unsigned short)(u >> 16);
}

template <int CTRL>
__device__ __forceinline__ float dpp_max(float v) {
  int o = __builtin_amdgcn_update_dpp(__float_as_int(v), __float_as_int(v), CTRL, 0xF, 0xF, false);
  return fmaxf(v, __int_as_float(o));
}

// ---------------------------------------------------------------------------
// Kernel 1 (fused): blocks 0..15 = FPS, 16..1039 = feature transpose,
// 1040..1048 = weight pack. FPS occupies only 16 CUs; the transpose/pack
// blocks ride the otherwise-idle CUs during the long FPS tail.
//
// FPS: 256 threads (4 waves), 16 pts/lane as PLAIN SCALAR float arrays with
// static indexing — the only formulation this toolchain keeps in registers
// (R3: VGPR=88 resident; f32x2 / 512-thr variants all spilled to 32-48).
// Per iteration: scalar dist update (bit-exact _rn) + per-lane max ->
// value-only DPP wave64 max -> 16 ballots + SALU ctz scan recover the
// lowest-index argmax -> lane0 publishes u64 key (distbits<<32 | ~idx) to a
// double-buffered slot -> ONE barrier -> all lanes max 4 keys -> coords via
// LDS broadcast read. Exact jnp.argmax tie-break semantics throughout.
// ---------------------------------------------------------------------------
struct FpsShared {
  float sx[NPTS], sy[NPTS], sz[NPTS];
  unsigned long long skey[2][4];
  float slog[3][MC];
};
struct TransShared {
  float tile[64][65];
};

__global__ __launch_bounds__(256, 1) void fused_pre(
    const float* __restrict__ points, const float* __restrict__ feats,
    const float* __restrict__ w1, const float* __restrict__ w2,
    const float* __restrict__ w3,
    unsigned short* __restrict__ featsT, unsigned short* __restrict__ wpack,
    float* __restrict__ out_cent) {
  __shared__ union { FpsShared f; TransShared tr; } S;
  const int blk = blockIdx.x;
  const int t = threadIdx.x;

  if (blk < 16) {
    // ======================= FPS =======================
    const int b = blk;
    const int w = t >> 6;
    const float* pb = points + (size_t)b * 3 * NPTS;

    // lane-owned idx for (k,c) = k*1024 + 4*t + c
    float fx[16], fy[16], fz[16], dist[16];
#pragma unroll
    for (int k = 0; k < 4; ++k) {
      float4 X = ((const float4*)pb)[k * 256 + t];
      float4 Y = ((const float4*)(pb + NPTS))[k * 256 + t];
      float4 Z = ((const float4*)(pb + 2 * NPTS))[k * 256 + t];
      ((float4*)S.f.sx)[k * 256 + t] = X;
      ((float4*)S.f.sy)[k * 256 + t] = Y;
      ((float4*)S.f.sz)[k * 256 + t] = Z;
      fx[k * 4 + 0] = X.x; fx[k * 4 + 1] = X.y; fx[k * 4 + 2] = X.z; fx[k * 4 + 3] = X.w;
      fy[k * 4 + 0] = Y.x; fy[k * 4 + 1] = Y.y; fy[k * 4 + 2] = Y.z; fy[k * 4 + 3] = Y.w;
      fz[k * 4 + 0] = Z.x; fz[k * 4 + 1] = Z.y; fz[k * 4 + 2] = Z.z; fz[k * 4 + 3] = Z.w;
    }
#pragma unroll
    for (int j = 0; j < 16; ++j) dist[j] = 1e10f;
    __syncthreads();

    float lx = S.f.sx[0], ly = S.f.sy[0], lz = S.f.sz[0];

    for (int i = 0; i < MC; ++i) {
      if (t == 0) { S.f.slog[0][i] = lx; S.f.slog[1][i] = ly; S.f.slog[2][i] = lz; }
      if (i == MC - 1) break;

      // ---- distance update (bit-exact, no contraction) + per-lane max ----
      float m = -1.0f;
#pragma unroll
      for (int j = 0; j < 16; ++j) {
        float dx = __fsub_rn(fx[j], lx);
        float dy = __fsub_rn(fy[j], ly);
        float dz = __fsub_rn(fz[j], lz);
        float d  = __fadd_rn(__fadd_rn(__fmul_rn(dx, dx), __fmul_rn(dy, dy)), __fmul_rn(dz, dz));
        float dm = fminf(dist[j], d);
        dist[j] = dm;
        m = fmaxf(m, dm);
      }

      // ---- value-only wave64 max via DPP (result in lane 63) ----
      m = dpp_max<0x111>(m);   // row_shr:1
      m = dpp_max<0x112>(m);   // row_shr:2
      m = dpp_max<0x114>(m);   // row_shr:4
      m = dpp_max<0x118>(m);   // row_shr:8
      m = dpp_max<0x142>(m);   // row_bcast:15
      m = dpp_max<0x143>(m);   // row_bcast:31
      const float wv = __int_as_float(__builtin_amdgcn_readlane(__float_as_int(m), 63));

      // ---- recover lowest matching index: 16 ballots + SALU scan ----
      // global idx = k*1024 + 4*(w*64+lane) + c: scan k asc, then lowest
      // lane (ctz), then lowest c — exact lowest-index tie-break.
      unsigned long long mk[4][4];
#pragma unroll
      for (int k = 0; k < 4; ++k) {
        mk[k][0] = __ballot(dist[k * 4 + 0] == wv);
        mk[k][1] = __ballot(dist[k * 4 + 1] == wv);
        mk[k][2] = __ballot(dist[k * 4 + 2] == wv);
        mk[k][3] = __ballot(dist[k * 4 + 3] == wv);
      }
      unsigned long long s0 = 0, s1 = 0, s2 = 0, s3 = 0, anyk = 0;
      int sk = -1;
#pragma unroll
      for (int k = 0; k < 4; ++k) {
        unsigned long long a = mk[k][0] | mk[k][1] | mk[k][2] | mk[k][3];
        if (sk < 0 && a != 0ull) {
          sk = k; anyk = a;
          s0 = mk[k][0]; s1 = mk[k][1]; s2 = mk[k][2]; s3 = mk[k][3];
        }
      }
      const int l = __builtin_ctzll(anyk);
      const unsigned long long bit = 1ull << l;
      const int c = (s0 & bit) ? 0 : (s1 & bit) ? 1 : (s2 & bit) ? 2 : 3;
      const int selIdx = sk * 1024 + 256 * w + 4 * l + c;

      const int nb = i & 1;
      if ((t & 63) == 0)
        S.f.skey[nb][w] = ((unsigned long long)__float_as_uint(wv) << 32) | (unsigned int)~selIdx;
      __syncthreads();

      // ---- all lanes: max of 4 keys, then LDS broadcast of winner coords ----
      unsigned long long k0 = S.f.skey[nb][0], k1 = S.f.skey[nb][1];
      unsigned long long k2 = S.f.skey[nb][2], k3 = S.f.skey[nb][3];
      unsigned long long ka = (k0 > k1) ? k0 : k1;
      unsigned long long kb = (k2 > k3) ? k2 : k3;
      unsigned long long km = (ka > kb) ? ka : kb;
      const int sel = (int)(~(unsigned int)km);
      lx = S.f.sx[sel]; ly = S.f.sy[sel]; lz = S.f.sz[sel];
    }
    __syncthreads();
    // coalesced centroid output [3][1024] per batch
    float* oc = out_cent + (size_t)b * 3 * MC;
#pragma unroll
    for (int k = 0; k < 12; ++k) {
      int idx = t + k * 256;
      oc[idx] = ((const float*)S.f.slog)[idx];
    }
  } else if (blk < 16 + 1024) {
    // ================== feature transpose ==================
    const int rel = blk - 16;
    const int b = rel >> 6;
    const int n0 = (rel & 63) * 64;
    const float* src = feats + (size_t)b * 64 * NPTS;
    {
      const int n = t & 63, cbase = t >> 6;
#pragma unroll
      for (int j = 0; j < 16; ++j) {
        int cc = cbase + j * 4;
        S.tr.tile[cc][n] = src[(size_t)cc * NPTS + n0 + n];
      }
    }
    __syncthreads();
    {
      const int cc = t & 63, nbase = t >> 6;
      unsigned short* dst = featsT + ((size_t)b * NPTS + n0) * 64;
#pragma unroll
      for (int j = 0; j < 16; ++j) {
        int n = nbase + j * 4;
        dst[(size_t)n * 64 + cc] = f2bf(S.tr.tile[cc][n]);
      }
    }
  } else {
    // ================== weight pack (f = 0..35) ==================
    const int f = (blk - (16 + 1024)) * 4 + (t >> 6);
    const int lane = t & 63;
    if (f < 36) {
      int layer, kt, nt;
      if (f < 12)      { layer = 0; kt = f >> 2;        nt = f & 3; }
      else if (f < 20) { layer = 1; kt = (f - 12) >> 2; nt = (f - 12) & 3; }
      else             { layer = 2; kt = (f - 20) >> 3; nt = (f - 20) & 7; }
      const int o = nt * 16 + (lane & 15);
      unsigned short* dst = wpack + ((size_t)f * 64 + lane) * 8;
#pragma unroll
      for (int j = 0; j < 8; ++j) {
        int k = kt * 32 + (lane >> 4) * 8 + j;
        float x = 0.0f;
        if (layer == 0)      { if (k < 67) { int cin = (k < 64) ? (k + 3) : (k - 64); x = w1[o * 67 + cin]; } }
        else if (layer == 1) { x = w2[o * 64 + k]; }
        else                 { x = w3[o * 64 + k]; }
        dst[j] = f2bf(x);
      }
    }
  }
}

// ---------------------------------------------------------------------------
// Kernel 2: ball query. Centroids read from out_cent layout [B,3,MC].
// ---------------------------------------------------------------------------
__global__ __launch_bounds__(256) void ball_query_kernel(const float* __restrict__ points,
                                                         const float* __restrict__ cent,
                                                         int* __restrict__ nidx) {
  __shared__ float sx[NPTS], sy[NPTS], sz[NPTS];
  __shared__ int lists[4][KNB];
  const int b  = blockIdx.x >> 4;
  const int cb = blockIdx.x & 15;
  const int t = threadIdx.x;
  const float* pb = points + (size_t)b * 3 * NPTS;
#pragma unroll
  for (int j = 0; j < 4; ++j) {
    int i4 = t + j * 256;
    ((float4*)sx)[i4] = ((const float4*)pb)[i4];
    ((float4*)sy)[i4] = ((const float4*)(pb + NPTS))[i4];
    ((float4*)sz)[i4] = ((const float4*)(pb + 2 * NPTS))[i4];
  }
  __syncthreads();
  const int w = t >> 6, lane = t & 63;
  const float R2 = (float)(0.2 * 0.2);
  const float* cbp = cent + (size_t)b * 3 * MC;
  for (int cm = 0; cm < 16; ++cm) {
    const int m  = cb * 64 + w * 16 + cm;
    const int bm = b * MC + m;
    const float cx = cbp[m], cy = cbp[MC + m], cz = cbp[2 * MC + m];
    const float c2 = __fadd_rn(__fadd_rn(__fmul_rn(cx, cx), __fmul_rn(cy, cy)), __fmul_rn(cz, cz));
    int cnt = 0;
    for (int ch = 0; ch < 64; ++ch) {
      const int n = ch * 64 + lane;
      float x = sx[n], y = sy[n], z = sz[n];
      float p2  = __fadd_rn(__fadd_rn(__fmul_rn(x, x),  __fmul_rn(y, y)),  __fmul_rn(z, z));
      float dot = __fadd_rn(__fadd_rn(__fmul_rn(cx, x), __fmul_rn(cy, y)), __fmul_rn(cz, z));
      float d2  = __fsub_rn(__fadd_rn(c2, p2), __fmul_rn(2.0f, dot));
      bool hit = (d2 <= R2);
      unsigned long long msk = __ballot(hit);
      if (hit) {
        int pos = cnt + __popcll(msk & ((1ull << lane) - 1ull));
        if (pos < KNB) lists[w][pos] = n;
      }
      cnt += __popcll(msk);
      if (cnt >= KNB) break;
    }
    if (lane < KNB) {
      int first = lists[w][0];
      int v = (lane < cnt) ? lists[w][lane] : first;
      nidx[(size_t)bm * KNB + lane] = v;
    }
  }
}

// ---------------------------------------------------------------------------
// Kernel 3: fused gather + 3-layer MLP (bf16 MFMA 16x16x32) + maxpool.
// ---------------------------------------------------------------------------
__global__ __launch_bounds__(256) void mlp_kernel(
    const float* __restrict__ points,
    const float* __restrict__ cent,
    const int* __restrict__ nidx,
    const unsigned short* __restrict__ featsT,
    const unsigned short* __restrict__ wpack,
    const float* __restrict__ b1, const float* __restrict__ g1, const float* __restrict__ be1,
    const float* __restrict__ b2, const float* __restrict__ g2, const float* __restrict__ be2,
    const float* __restrict__ b3, const float* __restrict__ g3, const float* __restrict__ be3,
    float* __restrict__ out) {
  __shared__ __align__(16) unsigned short Hs[4][2][32 * 72];
  __shared__ __align__(16) float obuf[128 * 20];
  const int t = threadIdx.x;
  const int w = t >> 6, lane = t & 63;
  const int r = lane & 15, q = lane >> 4;
  const float inv_s = 1.0f / sqrtf(1.0f + 1e-5f);

  float pb1[4], ps1[4], pe1[4], pb2[4], ps2[4], pe2[4], pb3[8], ps3[8], pe3[8];
#pragma unroll
  for (int nt = 0; nt < 4; ++nt) {
    int o = nt * 16 + r;
    pb1[nt] = b1[o]; ps1[nt] = g1[o] * inv_s; pe1[nt] = be1[o];
    pb2[nt] = b2[o]; ps2[nt] = g2[o] * inv_s; pe2[nt] = be2[o];
  }
#pragma unroll
  for (int nt = 0; nt < 8; ++nt) {
    int o = nt * 16 + r;
    pb3[nt] = b3[o]; ps3[nt] = g3[o] * inv_s; pe3[nt] = be3[o];
  }
  const int bm0 = blockIdx.x * 16;
  const int b   = bm0 >> 10;
  const int m0  = bm0 & 1023;
  const float* ptsb = points + (size_t)b * 3 * NPTS;
  const float* cbp  = cent + (size_t)b * 3 * MC;

  for (int it = 0; it < 4; ++it) {
    const int ml = it * 4 + w;
    const int bm = bm0 + ml;
    const int m  = bm & 1023;
    const int n0 = nidx[(size_t)bm * KNB + r];
    const int n1 = nidx[(size_t)bm * KNB + 16 + r];
    const float cx = cbp[m], cy = cbp[MC + m], cz = cbp[2 * MC + m];

    // ---- layer 1 ----
    bf16x8 aF[2][2];
#pragma unroll
    for (int mt = 0; mt < 2; ++mt) {
      int n = mt ? n1 : n0;
      const unsigned short* rowp = featsT + ((size_t)b * NPTS + n) * 64 + q * 8;
      aF[mt][0] = *(const bf16x8*)(rowp);
      aF[mt][1] = *(const bf16x8*)(rowp + 32);
    }
    bf16x8 aL[2];
#pragma unroll
    for (int mt = 0; mt < 2; ++mt) {
      bf16x8 a = {0, 0, 0, 0, 0, 0, 0, 0};
      if (q == 0) {
        int n = mt ? n1 : n0;
        a[0] = (short)f2bf(ptsb[n] - cx);
        a[1] = (short)f2bf(ptsb[NPTS + n] - cy);
        a[2] = (short)f2bf(ptsb[2 * NPTS + n] - cz);
      }
      aL[mt] = a;
    }
    f32x4 acc1[2][4];
#pragma unroll
    for (int mt = 0; mt < 2; ++mt)
#pragma unroll
      for (int nt = 0; nt < 4; ++nt) acc1[mt][nt] = (f32x4){0.f, 0.f, 0.f, 0.f};
#pragma unroll
    for (int kt = 0; kt < 3; ++kt) {
#pragma unroll
      for (int nt = 0; nt < 4; ++nt) {
        bf16x8 wf = *(const bf16x8*)(wpack + ((size_t)(kt * 4 + nt) * 64 + lane) * 8);
#pragma unroll
        for (int mt = 0; mt < 2; ++mt) {
          bf16x8 a = (kt < 2) ? aF[mt][kt] : aL[mt];
          acc1[mt][nt] = __builtin_amdgcn_mfma_f32_16x16x32_bf16(a, wf, acc1[mt][nt], 0, 0, 0);
        }
      }
    }
#pragma unroll
    for (int mt = 0; mt < 2; ++mt)
#pragma unroll
      for (int nt = 0; nt < 4; ++nt)
#pragma unroll
        for (int rr = 0; rr < 4; ++rr) {
          float y = (acc1[mt][nt][rr] + pb1[nt]) * ps1[nt] + pe1[nt];
          y = fmaxf(y, 0.0f);
          Hs[w][0][(mt * 16 + q * 4 + rr) * 72 + nt * 16 + r] = f2bf(y);
        }
    __threadfence_block();

    // ---- layer 2 ----
    f32x4 acc2[2][4];
#pragma unroll
    for (int mt = 0; mt < 2; ++mt)
#pragma unroll
      for (int nt = 0; nt < 4; ++nt) acc2[mt][nt] = (f32x4){0.f, 0.f, 0.f, 0.f};
#pragma unroll
    for (int kt = 0; kt < 2; ++kt) {
      bf16x8 a0 = *(const bf16x8*)&Hs[w][0][(0 * 16 + r) * 72 + kt * 32 + q * 8];
      bf16x8 a1 = *(const bf16x8*)&Hs[w][0][(1 * 16 + r) * 72 + kt * 32 + q * 8];
#pragma unroll
      for (int nt = 0; nt < 4; ++nt) {
        bf16x8 wf = *(const bf16x8*)(wpack + ((size_t)(12 + kt * 4 + nt) * 64 + lane) * 8);
        acc2[0][nt] = __builtin_amdgcn_mfma_f32_16x16x32_bf16(a0, wf, acc2[0][nt], 0, 0, 0);
        acc2[1][nt] = __builtin_amdgcn_mfma_f32_16x16x32_bf16(a1, wf, acc2[1][nt], 0, 0, 0);
      }
    }
#pragma unroll
    for (int mt = 0; mt < 2; ++mt)
#pragma unroll
      for (int nt = 0; nt < 4; ++nt)
#pragma unroll
        for (int rr = 0; rr < 4; ++rr) {
          float y = (acc2[mt][nt][rr] + pb2[nt]) * ps2[nt] + pe2[nt];
          y = fmaxf(y, 0.0f);
          Hs[w][1][(mt * 16 + q * 4 + rr) * 72 + nt * 16 + r] = f2bf(y);
        }
    __threadfence_block();

    // ---- layer 3 + maxpool ----
    f32x4 acc3[2][8];
#pragma unroll
    for (int mt = 0; mt < 2; ++mt)
#pragma unroll
      for (int nt = 0; nt < 8; ++nt) acc3[mt][nt] = (f32x4){0.f, 0.f, 0.f, 0.f};
#pragma unroll
    for (int kt = 0; kt < 2; ++kt) {
      bf16x8 a0 = *(const bf16x8*)&Hs[w][1][(0 * 16 + r) * 72 + kt * 32 + q * 8];
      bf16x8 a1 = *(const bf16x8*)&Hs[w][1][(1 * 16 + r) * 72 + kt * 32 + q * 8];
#pragma unroll
      for (int nt = 0; nt < 8; ++nt) {
        bf16x8 wf = *(const bf16x8*)(wpack + ((size_t)(20 + kt * 8 + nt) * 64 + lane) * 8);
        acc3[0][nt] = __builtin_amdgcn_mfma_f32_16x16x32_bf16(a0, wf, acc3[0][nt], 0, 0, 0);
        acc3[1][nt] = __builtin_amdgcn_mfma_f32_16x16x32_bf16(a1, wf, acc3[1][nt], 0, 0, 0);
      }
    }
#pragma unroll
    for (int nt = 0; nt < 8; ++nt) {
      float pm = 0.0f;   // relu outputs are >= 0
#pragma unroll
      for (int mt = 0; mt < 2; ++mt)
#pragma unroll
        for (int rr = 0; rr < 4; ++rr) {
          float y = (acc3[mt][nt][rr] + pb3[nt]) * ps3[nt] + pe3[nt];
          y = fmaxf(y, 0.0f);
          pm = fmaxf(pm, y);
        }
      pm = fmaxf(pm, __shfl_xor(pm, 16));
      pm = fmaxf(pm, __shfl_xor(pm, 32));
      if (q == 0) obuf[(nt * 16 + r) * 20 + ml] = pm;
    }
    __threadfence_block();
  }
  __syncthreads();
  // coalesced-ish store: thread t -> channel t>>1, half (t&1)*8
  {
    const int ch = t >> 1, mh = (t & 1) * 8;
    float4 u0 = *(const float4*)&obuf[ch * 20 + mh];
    float4 u1 = *(const float4*)&obuf[ch * 20 + mh + 4];
    float* outp = out + ((size_t)b * 128 + ch) * 1024 + m0 + mh;
    *(float4*)(outp)     = u0;
    *(float4*)(outp + 4) = u1;
  }
}

// ---------------------------------------------------------------------------
extern "C" void kernel_launch(void* const* d_in, const int* in_sizes, int n_in,
                              void* d_out, int out_size, void* d_ws, size_t ws_size,
                              hipStream_t stream) {
  (void)in_sizes; (void)n_in; (void)out_size; (void)ws_size;
  const float* points   = (const float*)d_in[0];
  const float* features = (const float*)d_in[1];
  const float* w1  = (const float*)d_in[2];
  const float* b1  = (const float*)d_in[3];
  const float* g1  = (const float*)d_in[4];
  const float* be1 = (const float*)d_in[5];
  const float* w2  = (const float*)d_in[6];
  const float* b2  = (const float*)d_in[7];
  const float* g2  = (const float*)d_in[8];
  const float* be2 = (const float*)d_in[9];
  const float* w3  = (const float*)d_in[10];
  const float* b3  = (const float*)d_in[11];
  const float* g3  = (const float*)d_in[12];
  const float* be3 = (const float*)d_in[13];

  float* outc = (float*)d_out;                  // centroids [16,3,1024]
  float* outf = outc + 16 * 3 * 1024;           // features  [16,128,1024]

  char* ws = (char*)d_ws;
  int*            nidx    = (int*)(ws);                      // 16384*32*4  = 2 MiB
  unsigned short* featsT  = (unsigned short*)(ws + 0x200000);// 16*4096*64*2= 8 MiB
  unsigned short* wpack   = (unsigned short*)(ws + 0xA00000);// 36*1024 B

  fused_pre<<<16 + 1024 + 9, 256, 0, stream>>>(points, features, w1, w2, w3,
                                               featsT, wpack, outc);
  ball_query_kernel<<<256, 256, 0, stream>>>(points, outc, nidx);
  mlp_kernel<<<1024, 256, 0, stream>>>(points, outc, nidx, featsT, wpack,
                                       b1, g1, be1, b2, g2, be2, b3, g3, be3, outf);
}